// Round 16
// baseline (200.342 us; speedup 1.0000x reference)
//
#include <hip/hip_runtime.h>

#define N_NODES 100000
#define IN_DIM 64
#define EMB 128
#define N_EDGES 1600000
#define BN_EPS 1e-5f

#define SCAN_ELEMS (N_NODES + 1)        // 100001
#define S1_EPB 1024
#define S1_BLOCKS ((SCAN_ELEMS + S1_EPB - 1) / S1_EPB)   // 98

// bucket partition
#define NB 98                 // buckets of 1024 dst each
#define BCAP 18432
#define FA_EPT 8
#define FA_BLK 2048
#define FA_GRID ((N_EDGES + FA_BLK - 1) / FA_BLK)   // 782

// ---- workspace layout (bytes) ----
#define WS_ROWSTART 0
#define WS_GSUM     400128
#define WS_GSUM2    400640
#define WS_BSUM     401152
#define WS_BCUR     401664
#define WS_CURSOR   402176
#define WS_PAIRS    802304                  // 12.8 MB
#define WS_AGG      13602304                // 25.6 MB
#define WS_DSTARR   39202304                // 7.2 MB   (dead after fillB -> reused as x16)
#define WS_SWARR    46427648                // 14.5 MB  (dead after fillB)
#define WS_X16      WS_DSTARR               // 12.8 MB fp16 x sidecar (fits in 21.7 MB dead)
#define WS_NEED_BUCKET 60878336ULL
#define WS_ZERO_BYTES 402176

typedef _Float16 half8_t __attribute__((ext_vector_type(8)));
typedef float floatx4 __attribute__((ext_vector_type(4)));

// ---------------- fillA: partition edges into 98 dst-buckets ----------------
__global__ __launch_bounds__(256) void fillA_kernel(
    const int* __restrict__ ei, const float* __restrict__ ew,
    int* __restrict__ bcur, int* __restrict__ dstArr, float2* __restrict__ swArr)
{
    __shared__ int cnt[NB], base[NB];
    const int tid = threadIdx.x;
    if (tid < NB) cnt[tid] = 0;
    __syncthreads();
    const int e0 = blockIdx.x * FA_BLK;
    int pk[FA_EPT];
    #pragma unroll
    for (int i = 0; i < FA_EPT; ++i) {
        int e = e0 + i * 256 + tid;
        pk[i] = -1;
        if (e < N_EDGES) {
            int d = ei[N_EDGES + e];
            int b = d >> 10;
            int pos = atomicAdd(&cnt[b], 1);   // LDS atomic
            pk[i] = (b << 12) | pos;
        }
    }
    __syncthreads();
    if (tid < NB) base[tid] = atomicAdd(&bcur[tid], cnt[tid]);
    __syncthreads();
    #pragma unroll
    for (int i = 0; i < FA_EPT; ++i) {
        int e = e0 + i * 256 + tid;
        if (pk[i] >= 0) {
            int b = pk[i] >> 12, pos = pk[i] & 0xFFF;
            int idx = b * BCAP + base[b] + pos;
            dstArr[idx] = ei[N_EDGES + e];
            swArr[idx]  = make_float2(__int_as_float(ei[e]), ew[e]);
        }
    }
}

// ---------------- histB: per-bucket LDS counting -> rowstart ----------------
__global__ __launch_bounds__(1024) void histB_kernel(
    const int* __restrict__ bcur, const int* __restrict__ dstArr,
    int* __restrict__ rowstart)
{
    __shared__ int cnt2[1024];
    const int g = blockIdx.x;
    const int tid = threadIdx.x;
    cnt2[tid] = 0;
    __syncthreads();
    const int nE = bcur[g];
    const int* seg = dstArr + g * BCAP;
    for (int j = tid; j < nE; j += 1024)
        atomicAdd(&cnt2[seg[j] & 1023], 1);
    __syncthreads();
    int node = g * 1024 + tid;
    if (node < N_NODES) rowstart[1 + node] = cnt2[tid];
}

// ---------------- fillB: LDS-cursor scatter into block-owned window ----------
__global__ __launch_bounds__(1024) void fillB_kernel(
    const int* __restrict__ bcur, const int* __restrict__ dstArr,
    const float2* __restrict__ swArr, const int* __restrict__ rowstart,
    float2* __restrict__ pairs)
{
    __shared__ int csr[1024];
    const int g = blockIdx.x;
    const int tid = threadIdx.x;
    int node = g * 1024 + tid;
    csr[tid] = (node < N_NODES) ? rowstart[node] : 0;
    __syncthreads();
    const int nE = bcur[g];
    const int base = g * BCAP;
    #pragma unroll 4
    for (int j = tid; j < nE; j += 1024) {
        int d = dstArr[base + j];
        int p = atomicAdd(&csr[d & 1023], 1);
        pairs[p] = swArr[base + j];
    }
}

// ---------------- cvt: x -> fp16 sidecar (runs after fillB frees the region) --
__global__ __launch_bounds__(256) void cvt_kernel(
    const float4* __restrict__ x4, ushort4* __restrict__ x16)
{
    int i = blockIdx.x * 256 + threadIdx.x;   // 1.6M float4 units
    if (i >= N_NODES * IN_DIM / 4) return;
    float4 v = x4[i];
    ushort4 u;
    _Float16 a = (_Float16)v.x, b = (_Float16)v.y,
             c = (_Float16)v.z, d = (_Float16)v.w;
    u.x = *(unsigned short*)&a; u.y = *(unsigned short*)&b;
    u.z = *(unsigned short*)&c; u.w = *(unsigned short*)&d;
    x16[i] = u;
}

// ---------------- 2a) per-block reduce of counts ----------------
__global__ __launch_bounds__(256) void scan1_kernel(
    const int* __restrict__ rowstart, int* __restrict__ bsum)
{
    __shared__ int red[256];
    const int t = threadIdx.x;
    const int base = blockIdx.x * S1_EPB + t * 4;
    int s = 0;
    #pragma unroll
    for (int k = 0; k < 4; ++k) {
        int idx = base + k;
        if (idx < SCAN_ELEMS) s += rowstart[idx];
    }
    red[t] = s;
    __syncthreads();
    for (int off = 128; off > 0; off >>= 1) {
        if (t < off) red[t] += red[t + off];
        __syncthreads();
    }
    if (t == 0) bsum[blockIdx.x] = red[0];
}

// ---------------- 2b) exclusive scan of block sums ----------------
__global__ __launch_bounds__(128) void scan2_kernel(int* __restrict__ bsum)
{
    __shared__ int buf[128];
    const int t = threadIdx.x;
    buf[t] = (t < S1_BLOCKS) ? bsum[t] : 0;
    __syncthreads();
    for (int off = 1; off < 128; off <<= 1) {
        int v = (t >= off) ? buf[t - off] : 0;
        __syncthreads();
        buf[t] += v;
        __syncthreads();
    }
    if (t < S1_BLOCKS) bsum[t] = (t > 0) ? buf[t - 1] : 0;
}

// ---------------- 2c) block-local inclusive scan + offset ----------------
__global__ __launch_bounds__(256) void scan3_kernel(
    int* __restrict__ rowstart, int* __restrict__ cursor,
    const int* __restrict__ bsum)
{
    __shared__ int tsum[256];
    const int t = threadIdx.x;
    const int base = blockIdx.x * S1_EPB + t * 4;
    int c0 = 0, c1 = 0, c2 = 0, c3 = 0;
    if (base + 0 < SCAN_ELEMS) c0 = rowstart[base + 0];
    if (base + 1 < SCAN_ELEMS) c1 = rowstart[base + 1];
    if (base + 2 < SCAN_ELEMS) c2 = rowstart[base + 2];
    if (base + 3 < SCAN_ELEMS) c3 = rowstart[base + 3];
    const int i0 = c0, i1 = i0 + c1, i2 = i1 + c2, i3 = i2 + c3;
    tsum[t] = i3;
    __syncthreads();
    for (int off = 1; off < 256; off <<= 1) {
        int v = (t >= off) ? tsum[t - off] : 0;
        __syncthreads();
        tsum[t] += v;
        __syncthreads();
    }
    const int boff = bsum[blockIdx.x] + tsum[t] - i3;
    const int r0 = boff + i0, r1 = boff + i1, r2 = boff + i2, r3 = boff + i3;
    if (base + 0 < SCAN_ELEMS) rowstart[base + 0] = r0;
    if (base + 1 < SCAN_ELEMS) rowstart[base + 1] = r1;
    if (base + 2 < SCAN_ELEMS) rowstart[base + 2] = r2;
    if (base + 3 < SCAN_ELEMS) rowstart[base + 3] = r3;
    if (base + 0 < N_NODES) cursor[base + 0] = r0;
    if (base + 1 < N_NODES) cursor[base + 1] = r1;
    if (base + 2 < N_NODES) cursor[base + 2] = r2;
    if (base + 3 < N_NODES) cursor[base + 3] = r3;
}

// ---------------- gather (fp16 x): agg[n] = sum w * x16[src]  ----------------
// r15: BW-bound (FETCH 183 MB @3.3 TB/s, occ 66%). fp16 rows halve logical
// bytes (410->205 MB) and double L2-resident fraction (12.8 MB / 32 MB L2).
#define G_NPW 5
__global__ __launch_bounds__(256) void gather_kernel(
    const _Float16* __restrict__ x16,
    const int* __restrict__ rowstart,
    const float2* __restrict__ pairs,
    float* __restrict__ agg)
{
    const int tid  = threadIdx.x;
    const int lane = tid & 63;
    const int wid  = tid >> 6;
    const int node0 = (blockIdx.x * 4 + wid) * G_NPW;

    for (int r = 0; r < G_NPW; ++r) {
        const int n  = node0 + r;
        const int jb = rowstart[n];
        const int je = rowstart[n + 1];
        float accA = 0.f, accB = 0.f;
        for (int j0 = jb; j0 < je; j0 += 64) {
            const int cnt = min(64, je - j0);
            float2 p = (lane < cnt) ? pairs[j0 + lane] : make_float2(0.f, 0.f);
            int   psrc = __float_as_int(p.x);
            float pw   = p.y;
            const int nch = (cnt + 15) >> 4;
            for (int c = 0; c < nch; ++c) {
                const int base = c * 16;
                #pragma unroll
                for (int t = 0; t < 16; t += 2) {
                    int   sA = __shfl(psrc, base + t);
                    float wA = __shfl(pw,   base + t);
                    int   sB = __shfl(psrc, base + t + 1);
                    float wB = __shfl(pw,   base + t + 1);
                    accA += wA * (float)x16[(size_t)sA * IN_DIM + lane];
                    accB += wB * (float)x16[(size_t)sB * IN_DIM + lane];
                }
            }
        }
        agg[(size_t)n * IN_DIM + lane] = accA + accB;
    }
}

// ---------------- gemv (MFMA): h = (agg + x) @ W1 + b1, + BN partials --------
#define GM_ITERS 5
#define GM_ROWS (32 * GM_ITERS)   // 160 rows/block -> 625 blocks
__global__ __launch_bounds__(256) void gemv_kernel(
    const float* __restrict__ agg,
    const float* __restrict__ x,
    const float* __restrict__ W1,   // [64,128] row-major, fp32
    const float* __restrict__ b1,
    float* __restrict__ h,          // [N,128]
    float* __restrict__ gsum, float* __restrict__ gsum2)
{
    __shared__ _Float16 Ah[32][72];
    __shared__ float redS[EMB], redQ[EMB];

    const int tid  = threadIdx.x;
    const int lane = tid & 63;
    const int wid  = tid >> 6;
    const int rg   = wid >> 1;
    const int ch   = wid & 1;
    const int c0w  = ch * 64;
    const int l15  = lane & 15;
    const int kb   = lane >> 4;

    half8_t Bf[4][2];
    #pragma unroll
    for (int ct = 0; ct < 4; ++ct)
        #pragma unroll
        for (int kc = 0; kc < 2; ++kc)
            #pragma unroll
            for (int i = 0; i < 8; ++i)
                Bf[ct][kc][i] = (_Float16)W1[(kc * 32 + kb * 8 + i) * EMB + ct * 16 + c0w + l15];
    float b1c[4];
    #pragma unroll
    for (int ct = 0; ct < 4; ++ct) b1c[ct] = b1[ct * 16 + c0w + l15];

    if (tid < EMB) { redS[tid] = 0.f; redQ[tid] = 0.f; }

    float sAcc[4] = {0.f, 0.f, 0.f, 0.f};
    float qAcc[4] = {0.f, 0.f, 0.f, 0.f};

    const int r0blk = blockIdx.x * GM_ROWS;
    for (int it = 0; it < GM_ITERS; ++it) {
        const int r0 = r0blk + it * 32;
        __syncthreads();
        #pragma unroll
        for (int i = 0; i < 2; ++i) {
            int j   = i * 256 + tid;
            int row = j >> 4;
            int c4  = (j & 15) * 4;
            float4 av = *(const float4*)&agg[(size_t)(r0 + row) * IN_DIM + c4];
            float4 xv = *(const float4*)&x[(size_t)(r0 + row) * IN_DIM + c4];
            Ah[row][c4 + 0] = (_Float16)(av.x + xv.x);
            Ah[row][c4 + 1] = (_Float16)(av.y + xv.y);
            Ah[row][c4 + 2] = (_Float16)(av.z + xv.z);
            Ah[row][c4 + 3] = (_Float16)(av.w + xv.w);
        }
        __syncthreads();

        floatx4 acc[4];
        #pragma unroll
        for (int ct = 0; ct < 4; ++ct)
            acc[ct] = (floatx4){b1c[ct], b1c[ct], b1c[ct], b1c[ct]};
        #pragma unroll
        for (int kc = 0; kc < 2; ++kc) {
            half8_t af = *(half8_t*)&Ah[rg * 16 + l15][kc * 32 + kb * 8];
            #pragma unroll
            for (int ct = 0; ct < 4; ++ct)
                acc[ct] = __builtin_amdgcn_mfma_f32_16x16x32_f16(af, Bf[ct][kc], acc[ct], 0, 0, 0);
        }

        #pragma unroll
        for (int ct = 0; ct < 4; ++ct) {
            #pragma unroll
            for (int i = 0; i < 4; ++i) {
                int row = r0 + rg * 16 + kb * 4 + i;
                float v = acc[ct][i];
                h[(size_t)row * EMB + c0w + ct * 16 + l15] = v;
                sAcc[ct] += v;
                qAcc[ct] += v * v;
            }
        }
    }

    __syncthreads();
    #pragma unroll
    for (int ct = 0; ct < 4; ++ct) {
        atomicAdd(&redS[c0w + ct * 16 + l15], sAcc[ct]);
        atomicAdd(&redQ[c0w + ct * 16 + l15], qAcc[ct]);
    }
    __syncthreads();
    if (tid < EMB) {
        atomicAdd(&gsum[tid],  redS[tid]);
        atomicAdd(&gsum2[tid], redQ[tid]);
    }
}

// ---------------- out = relu(BN(h)) @ W2 + b2, fp16 MFMA (in-place) --------
#define MR 32
#define M2_ITERS 5
#define M2_ROWS (MR * M2_ITERS)   // 160 rows/block -> 625 blocks

__global__ __launch_bounds__(256) void mlp2_kernel(
    float* __restrict__ hio,
    const float* __restrict__ gsum, const float* __restrict__ gsum2,
    const float* __restrict__ gamma, const float* __restrict__ beta,
    const float* __restrict__ W2,   // [128,128] row-major, fp32
    const float* __restrict__ b2)
{
    __shared__ _Float16 Ph[MR][136];
    __shared__ float abuf[EMB], bbuf[EMB];

    const int tid  = threadIdx.x;
    const int lane = tid & 63;
    const int wid  = tid >> 6;
    const int rg   = wid >> 1;
    const int ch   = wid & 1;
    const int c0w  = ch * 64;
    const int l15  = lane & 15;
    const int kb   = lane >> 4;

    if (tid < EMB) {
        const float invN = 1.0f / (float)N_NODES;
        float mean = gsum[tid] * invN;
        float var  = gsum2[tid] * invN - mean * mean;
        float inv  = rsqrtf(var + BN_EPS);
        float a    = gamma[tid] * inv;
        abuf[tid] = a;
        bbuf[tid] = beta[tid] - mean * a;
    }

    const int bcol = c0w + l15;
    half8_t Bf[4][4];
    #pragma unroll
    for (int ct = 0; ct < 4; ++ct) {
        #pragma unroll
        for (int kc = 0; kc < 4; ++kc) {
            #pragma unroll
            for (int i = 0; i < 8; ++i)
                Bf[ct][kc][i] = (_Float16)W2[(kc * 32 + kb * 8 + i) * EMB + ct * 16 + bcol];
        }
    }
    float b2c[4];
    #pragma unroll
    for (int ct = 0; ct < 4; ++ct) b2c[ct] = b2[ct * 16 + bcol];

    __syncthreads();

    const int r0blk = blockIdx.x * M2_ROWS;
    for (int it = 0; it < M2_ITERS; ++it) {
        const int r0 = r0blk + it * MR;
        #pragma unroll
        for (int i = 0; i < 8; ++i) {
            int j   = i * 256 + tid;
            int row = j >> 6;
            int c2  = (j & 63) * 2;
            const float2 hv = *(const float2*)&hio[(size_t)(r0 + row) * EMB + c2];
            float p0 = fmaxf(hv.x * abuf[c2]     + bbuf[c2],     0.f);
            float p1 = fmaxf(hv.y * abuf[c2 + 1] + bbuf[c2 + 1], 0.f);
            Ph[row][c2]     = (_Float16)p0;
            Ph[row][c2 + 1] = (_Float16)p1;
        }
        __syncthreads();

        floatx4 acc[4];
        #pragma unroll
        for (int ct = 0; ct < 4; ++ct)
            acc[ct] = (floatx4){b2c[ct], b2c[ct], b2c[ct], b2c[ct]};
        #pragma unroll
        for (int kc = 0; kc < 4; ++kc) {
            half8_t af = *(half8_t*)&Ph[rg * 16 + l15][kc * 32 + kb * 8];
            #pragma unroll
            for (int ct = 0; ct < 4; ++ct)
                acc[ct] = __builtin_amdgcn_mfma_f32_16x16x32_f16(af, Bf[ct][kc], acc[ct], 0, 0, 0);
        }
        __syncthreads();

        #pragma unroll
        for (int ct = 0; ct < 4; ++ct) {
            #pragma unroll
            for (int i = 0; i < 4; ++i) {
                int row = r0 + rg * 16 + kb * 4 + i;
                hio[(size_t)row * EMB + c0w + ct * 16 + l15] = acc[ct][i];
            }
        }
    }
}

extern "C" void kernel_launch(void* const* d_in, const int* in_sizes, int n_in,
                              void* d_out, int out_size, void* d_ws, size_t ws_size,
                              hipStream_t stream)
{
    const float* x     = (const float*)d_in[0];
    const int*   ei    = (const int*)d_in[1];   // int32 [2,E]
    const float* ew    = (const float*)d_in[3];
    const float* W1    = (const float*)d_in[4];
    const float* b1    = (const float*)d_in[5];
    const float* gamma = (const float*)d_in[6];
    const float* beta  = (const float*)d_in[7];
    const float* W2    = (const float*)d_in[8];
    const float* b2    = (const float*)d_in[9];

    char* ws = (char*)d_ws;
    int*      rowstart = (int*)(ws + WS_ROWSTART);
    float*    gsum     = (float*)(ws + WS_GSUM);
    float*    gsum2    = (float*)(ws + WS_GSUM2);
    int*      bsum     = (int*)(ws + WS_BSUM);
    int*      bcur     = (int*)(ws + WS_BCUR);
    int*      cursor   = (int*)(ws + WS_CURSOR);
    float2*   pairs    = (float2*)(ws + WS_PAIRS);
    float*    agg      = (float*)(ws + WS_AGG);
    int*      dstArr   = (int*)(ws + WS_DSTARR);
    float2*   swArr    = (float2*)(ws + WS_SWARR);
    _Float16* x16      = (_Float16*)(ws + WS_X16);   // overlays dstArr (dead after fillB)
    float*    h        = (float*)d_out;

    hipMemsetAsync(d_ws, 0, WS_ZERO_BYTES, stream);

    fillA_kernel<<<FA_GRID, 256, 0, stream>>>(ei, ew, bcur, dstArr, swArr);
    histB_kernel<<<NB, 1024, 0, stream>>>(bcur, dstArr, rowstart);
    scan1_kernel<<<S1_BLOCKS, 256, 0, stream>>>(rowstart, bsum);
    scan2_kernel<<<1, 128, 0, stream>>>(bsum);
    scan3_kernel<<<S1_BLOCKS, 256, 0, stream>>>(rowstart, cursor, bsum);
    fillB_kernel<<<NB, 1024, 0, stream>>>(bcur, dstArr, swArr, rowstart, pairs);
    // dstArr/swArr now dead -> write x16 into that region
    cvt_kernel<<<(N_NODES * IN_DIM / 4 + 255) / 256, 256, 0, stream>>>(
        (const float4*)x, (ushort4*)x16);
    gather_kernel<<<N_NODES / (4 * G_NPW), 256, 0, stream>>>(x16, rowstart, pairs, agg);
    gemv_kernel<<<N_NODES / GM_ROWS, 256, 0, stream>>>(agg, x, W1, b1, h, gsum, gsum2);
    mlp2_kernel<<<N_NODES / M2_ROWS, 256, 0, stream>>>(h, gsum, gsum2, gamma, beta, W2, b2);
}

// Round 17
// 187.772 us; speedup vs baseline: 1.0669x; 1.0669x over previous
//
#include <hip/hip_runtime.h>

#define N_NODES 100000
#define IN_DIM 64
#define EMB 128
#define N_EDGES 1600000
#define BN_EPS 1e-5f

// bucket partition
#define NB 98                 // buckets of 1024 dst each
#define BCAP 18432
#define FA_EPT 8
#define FA_BLK 2048
#define FA_GRID ((N_EDGES + FA_BLK - 1) / FA_BLK)   // 782

// ---- workspace layout (bytes) ----
#define WS_ROWSTART 0
#define WS_GSUM     400128
#define WS_GSUM2    400640
#define WS_BCUR     401152
#define WS_PAIRS    802304                  // 12.8 MB
#define WS_AGG      13602304                // 25.6 MB
#define WS_DSTARR   39202304                // 7.2 MB
#define WS_SWARR    46427648                // 14.5 MB
#define WS_NEED_BUCKET 60878336ULL
#define WS_ZERO_BYTES 402176

typedef _Float16 half8_t __attribute__((ext_vector_type(8)));
typedef float floatx4 __attribute__((ext_vector_type(4)));

// ---------------- fillA: partition edges into 98 dst-buckets ----------------
__global__ __launch_bounds__(256) void fillA_kernel(
    const int* __restrict__ ei, const float* __restrict__ ew,
    int* __restrict__ bcur, int* __restrict__ dstArr, float2* __restrict__ swArr)
{
    __shared__ int cnt[NB], base[NB];
    const int tid = threadIdx.x;
    if (tid < NB) cnt[tid] = 0;
    __syncthreads();
    const int e0 = blockIdx.x * FA_BLK;
    int pk[FA_EPT];
    #pragma unroll
    for (int i = 0; i < FA_EPT; ++i) {
        int e = e0 + i * 256 + tid;
        pk[i] = -1;
        if (e < N_EDGES) {
            int d = ei[N_EDGES + e];
            int b = d >> 10;
            int pos = atomicAdd(&cnt[b], 1);   // LDS atomic
            pk[i] = (b << 12) | pos;
        }
    }
    __syncthreads();
    if (tid < NB) base[tid] = atomicAdd(&bcur[tid], cnt[tid]);
    __syncthreads();
    #pragma unroll
    for (int i = 0; i < FA_EPT; ++i) {
        int e = e0 + i * 256 + tid;
        if (pk[i] >= 0) {
            int b = pk[i] >> 12, pos = pk[i] & 0xFFF;
            int idx = b * BCAP + base[b] + pos;
            dstArr[idx] = ei[N_EDGES + e];
            swArr[idx]  = make_float2(__int_as_float(ei[e]), ew[e]);
        }
    }
}

// ---------------- fillB2: hist + scan + rowstart + scatter, all in one ------
// Block g: bucket base from scanning bcur (98 ints); LDS histogram of its
// segment; LDS scan of 1024 counts; writes rowstart for its node range;
// LDS-cursor scatter into its block-owned pairs window.
__global__ __launch_bounds__(1024) void fillB2_kernel(
    const int* __restrict__ bcur, const int* __restrict__ dstArr,
    const float2* __restrict__ swArr,
    int* __restrict__ rowstart, float2* __restrict__ pairs)
{
    __shared__ int cnt2[1024];
    __shared__ int pre[1024];
    __shared__ int sbk[128];
    const int g = blockIdx.x;
    const int tid = threadIdx.x;

    // bucket base = exclusive prefix of bcur over buckets < g
    if (tid < 128) sbk[tid] = (tid < NB) ? bcur[tid] : 0;
    cnt2[tid] = 0;
    __syncthreads();
    for (int off = 1; off < 128; off <<= 1) {
        int v = 0;
        if (tid < 128 && tid >= off) v = sbk[tid - off];
        __syncthreads();
        if (tid < 128) sbk[tid] += v;
        __syncthreads();
    }
    const int bucketBase = (g > 0) ? sbk[g - 1] : 0;

    // histogram this bucket's segment
    const int nE = bcur[g];
    const int segBase = g * BCAP;
    for (int j = tid; j < nE; j += 1024)
        atomicAdd(&cnt2[dstArr[segBase + j] & 1023], 1);   // LDS atomic
    __syncthreads();

    // LDS scan of 1024 counts -> per-node start
    const int c = cnt2[tid];
    pre[tid] = c;
    __syncthreads();
    for (int off = 1; off < 1024; off <<= 1) {
        int v = (tid >= off) ? pre[tid - off] : 0;
        __syncthreads();
        pre[tid] += v;
        __syncthreads();
    }
    const int start = bucketBase + pre[tid] - c;   // exclusive
    const int node = g * 1024 + tid;
    if (node < N_NODES) rowstart[node] = start;
    if (node == N_NODES - 1) rowstart[N_NODES] = start + c;

    // cursors and scatter
    __syncthreads();
    cnt2[tid] = start;
    __syncthreads();
    #pragma unroll 4
    for (int j = tid; j < nE; j += 1024) {
        int d = dstArr[segBase + j];
        int p = atomicAdd(&cnt2[d & 1023], 1);   // LDS atomic, block-owned range
        pairs[p] = swArr[segBase + j];
    }
}

// ---------------- gather: agg[n] = sum w * x[src]  (fp32, chunk-8) ----------
// r15/r16 A/B: fp16 halved FETCH but time unchanged -> issue-bound, not bytes.
// Chunk 8 cuts Poisson-degree padding inflation 1.47x -> 1.25x.
#define G_NPW 5
__global__ __launch_bounds__(256) void gather_kernel(
    const float* __restrict__ x,
    const int* __restrict__ rowstart,
    const float2* __restrict__ pairs,
    float* __restrict__ agg)
{
    const int tid  = threadIdx.x;
    const int lane = tid & 63;
    const int wid  = tid >> 6;
    const int node0 = (blockIdx.x * 4 + wid) * G_NPW;

    for (int r = 0; r < G_NPW; ++r) {
        const int n  = node0 + r;
        const int jb = rowstart[n];
        const int je = rowstart[n + 1];
        float accA = 0.f, accB = 0.f;
        for (int j0 = jb; j0 < je; j0 += 64) {
            const int cnt = min(64, je - j0);
            float2 p = (lane < cnt) ? pairs[j0 + lane] : make_float2(0.f, 0.f);
            int   psrc = __float_as_int(p.x);
            float pw   = p.y;
            const int nch = (cnt + 7) >> 3;
            for (int c = 0; c < nch; ++c) {
                const int base = c * 8;
                #pragma unroll
                for (int t = 0; t < 8; t += 2) {
                    int   sA = __shfl(psrc, base + t);
                    float wA = __shfl(pw,   base + t);
                    int   sB = __shfl(psrc, base + t + 1);
                    float wB = __shfl(pw,   base + t + 1);
                    accA += wA * x[(unsigned)(sA * IN_DIM + lane)];
                    accB += wB * x[(unsigned)(sB * IN_DIM + lane)];
                }
            }
        }
        agg[(size_t)n * IN_DIM + lane] = accA + accB;
    }
}

// ---------------- gemv (MFMA): h = (agg + x) @ W1 + b1, + BN partials --------
#define GM_ITERS 5
#define GM_ROWS (32 * GM_ITERS)   // 160 rows/block -> 625 blocks
__global__ __launch_bounds__(256) void gemv_kernel(
    const float* __restrict__ agg,
    const float* __restrict__ x,
    const float* __restrict__ W1,   // [64,128] row-major, fp32
    const float* __restrict__ b1,
    float* __restrict__ h,          // [N,128]
    float* __restrict__ gsum, float* __restrict__ gsum2)
{
    __shared__ _Float16 Ah[32][72];
    __shared__ float redS[EMB], redQ[EMB];

    const int tid  = threadIdx.x;
    const int lane = tid & 63;
    const int wid  = tid >> 6;
    const int rg   = wid >> 1;
    const int ch   = wid & 1;
    const int c0w  = ch * 64;
    const int l15  = lane & 15;
    const int kb   = lane >> 4;

    half8_t Bf[4][2];
    #pragma unroll
    for (int ct = 0; ct < 4; ++ct)
        #pragma unroll
        for (int kc = 0; kc < 2; ++kc)
            #pragma unroll
            for (int i = 0; i < 8; ++i)
                Bf[ct][kc][i] = (_Float16)W1[(kc * 32 + kb * 8 + i) * EMB + ct * 16 + c0w + l15];
    float b1c[4];
    #pragma unroll
    for (int ct = 0; ct < 4; ++ct) b1c[ct] = b1[ct * 16 + c0w + l15];

    if (tid < EMB) { redS[tid] = 0.f; redQ[tid] = 0.f; }

    float sAcc[4] = {0.f, 0.f, 0.f, 0.f};
    float qAcc[4] = {0.f, 0.f, 0.f, 0.f};

    const int r0blk = blockIdx.x * GM_ROWS;
    for (int it = 0; it < GM_ITERS; ++it) {
        const int r0 = r0blk + it * 32;
        __syncthreads();
        #pragma unroll
        for (int i = 0; i < 2; ++i) {
            int j   = i * 256 + tid;
            int row = j >> 4;
            int c4  = (j & 15) * 4;
            float4 av = *(const float4*)&agg[(size_t)(r0 + row) * IN_DIM + c4];
            float4 xv = *(const float4*)&x[(size_t)(r0 + row) * IN_DIM + c4];
            Ah[row][c4 + 0] = (_Float16)(av.x + xv.x);
            Ah[row][c4 + 1] = (_Float16)(av.y + xv.y);
            Ah[row][c4 + 2] = (_Float16)(av.z + xv.z);
            Ah[row][c4 + 3] = (_Float16)(av.w + xv.w);
        }
        __syncthreads();

        floatx4 acc[4];
        #pragma unroll
        for (int ct = 0; ct < 4; ++ct)
            acc[ct] = (floatx4){b1c[ct], b1c[ct], b1c[ct], b1c[ct]};
        #pragma unroll
        for (int kc = 0; kc < 2; ++kc) {
            half8_t af = *(half8_t*)&Ah[rg * 16 + l15][kc * 32 + kb * 8];
            #pragma unroll
            for (int ct = 0; ct < 4; ++ct)
                acc[ct] = __builtin_amdgcn_mfma_f32_16x16x32_f16(af, Bf[ct][kc], acc[ct], 0, 0, 0);
        }

        #pragma unroll
        for (int ct = 0; ct < 4; ++ct) {
            #pragma unroll
            for (int i = 0; i < 4; ++i) {
                int row = r0 + rg * 16 + kb * 4 + i;
                float v = acc[ct][i];
                h[(size_t)row * EMB + c0w + ct * 16 + l15] = v;
                sAcc[ct] += v;
                qAcc[ct] += v * v;
            }
        }
    }

    __syncthreads();
    #pragma unroll
    for (int ct = 0; ct < 4; ++ct) {
        atomicAdd(&redS[c0w + ct * 16 + l15], sAcc[ct]);
        atomicAdd(&redQ[c0w + ct * 16 + l15], qAcc[ct]);
    }
    __syncthreads();
    if (tid < EMB) {
        atomicAdd(&gsum[tid],  redS[tid]);
        atomicAdd(&gsum2[tid], redQ[tid]);
    }
}

// ---------------- out = relu(BN(h)) @ W2 + b2, fp16 MFMA (in-place) --------
#define MR 32
#define M2_ITERS 5
#define M2_ROWS (MR * M2_ITERS)   // 160 rows/block -> 625 blocks

__global__ __launch_bounds__(256) void mlp2_kernel(
    float* __restrict__ hio,
    const float* __restrict__ gsum, const float* __restrict__ gsum2,
    const float* __restrict__ gamma, const float* __restrict__ beta,
    const float* __restrict__ W2,   // [128,128] row-major, fp32
    const float* __restrict__ b2)
{
    __shared__ _Float16 Ph[MR][136];
    __shared__ float abuf[EMB], bbuf[EMB];

    const int tid  = threadIdx.x;
    const int lane = tid & 63;
    const int wid  = tid >> 6;
    const int rg   = wid >> 1;
    const int ch   = wid & 1;
    const int c0w  = ch * 64;
    const int l15  = lane & 15;
    const int kb   = lane >> 4;

    if (tid < EMB) {
        const float invN = 1.0f / (float)N_NODES;
        float mean = gsum[tid] * invN;
        float var  = gsum2[tid] * invN - mean * mean;
        float inv  = rsqrtf(var + BN_EPS);
        float a    = gamma[tid] * inv;
        abuf[tid] = a;
        bbuf[tid] = beta[tid] - mean * a;
    }

    const int bcol = c0w + l15;
    half8_t Bf[4][4];
    #pragma unroll
    for (int ct = 0; ct < 4; ++ct) {
        #pragma unroll
        for (int kc = 0; kc < 4; ++kc) {
            #pragma unroll
            for (int i = 0; i < 8; ++i)
                Bf[ct][kc][i] = (_Float16)W2[(kc * 32 + kb * 8 + i) * EMB + ct * 16 + bcol];
        }
    }
    float b2c[4];
    #pragma unroll
    for (int ct = 0; ct < 4; ++ct) b2c[ct] = b2[ct * 16 + bcol];

    __syncthreads();

    const int r0blk = blockIdx.x * M2_ROWS;
    for (int it = 0; it < M2_ITERS; ++it) {
        const int r0 = r0blk + it * MR;
        #pragma unroll
        for (int i = 0; i < 8; ++i) {
            int j   = i * 256 + tid;
            int row = j >> 6;
            int c2  = (j & 63) * 2;
            const float2 hv = *(const float2*)&hio[(size_t)(r0 + row) * EMB + c2];
            float p0 = fmaxf(hv.x * abuf[c2]     + bbuf[c2],     0.f);
            float p1 = fmaxf(hv.y * abuf[c2 + 1] + bbuf[c2 + 1], 0.f);
            Ph[row][c2]     = (_Float16)p0;
            Ph[row][c2 + 1] = (_Float16)p1;
        }
        __syncthreads();

        floatx4 acc[4];
        #pragma unroll
        for (int ct = 0; ct < 4; ++ct)
            acc[ct] = (floatx4){b2c[ct], b2c[ct], b2c[ct], b2c[ct]};
        #pragma unroll
        for (int kc = 0; kc < 4; ++kc) {
            half8_t af = *(half8_t*)&Ph[rg * 16 + l15][kc * 32 + kb * 8];
            #pragma unroll
            for (int ct = 0; ct < 4; ++ct)
                acc[ct] = __builtin_amdgcn_mfma_f32_16x16x32_f16(af, Bf[ct][kc], acc[ct], 0, 0, 0);
        }
        __syncthreads();

        #pragma unroll
        for (int ct = 0; ct < 4; ++ct) {
            #pragma unroll
            for (int i = 0; i < 4; ++i) {
                int row = r0 + rg * 16 + kb * 4 + i;
                hio[(size_t)row * EMB + c0w + ct * 16 + l15] = acc[ct][i];
            }
        }
    }
}

extern "C" void kernel_launch(void* const* d_in, const int* in_sizes, int n_in,
                              void* d_out, int out_size, void* d_ws, size_t ws_size,
                              hipStream_t stream)
{
    const float* x     = (const float*)d_in[0];
    const int*   ei    = (const int*)d_in[1];   // int32 [2,E]
    const float* ew    = (const float*)d_in[3];
    const float* W1    = (const float*)d_in[4];
    const float* b1    = (const float*)d_in[5];
    const float* gamma = (const float*)d_in[6];
    const float* beta  = (const float*)d_in[7];
    const float* W2    = (const float*)d_in[8];
    const float* b2    = (const float*)d_in[9];

    char* ws = (char*)d_ws;
    int*    rowstart = (int*)(ws + WS_ROWSTART);
    float*  gsum     = (float*)(ws + WS_GSUM);
    float*  gsum2    = (float*)(ws + WS_GSUM2);
    int*    bcur     = (int*)(ws + WS_BCUR);
    float2* pairs    = (float2*)(ws + WS_PAIRS);
    float*  agg      = (float*)(ws + WS_AGG);
    int*    dstArr   = (int*)(ws + WS_DSTARR);
    float2* swArr    = (float2*)(ws + WS_SWARR);
    float*  h        = (float*)d_out;

    hipMemsetAsync(d_ws, 0, WS_ZERO_BYTES, stream);

    fillA_kernel<<<FA_GRID, 256, 0, stream>>>(ei, ew, bcur, dstArr, swArr);
    fillB2_kernel<<<NB, 1024, 0, stream>>>(bcur, dstArr, swArr, rowstart, pairs);
    gather_kernel<<<N_NODES / (4 * G_NPW), 256, 0, stream>>>(x, rowstart, pairs, agg);
    gemv_kernel<<<N_NODES / GM_ROWS, 256, 0, stream>>>(agg, x, W1, b1, h, gsum, gsum2);
    mlp2_kernel<<<N_NODES / M2_ROWS, 256, 0, stream>>>(h, gsum, gsum2, gamma, beta, W2, b2);
}